// Round 8
// baseline (586.060 us; speedup 1.0000x reference)
//
#include <hip/hip_runtime.h>

typedef unsigned long long u64;
typedef unsigned int u32;
typedef unsigned short u16;

#define N_ROWS 16384
#define DIM    512
#define K_CODES 8192

#define CHUNKS 32
#define CHUNK_CODES 256
#define BMS 256
#define KC 32
#define KSTAGES (DIM / KC)   // 16

typedef short bf16x8 __attribute__((ext_vector_type(8)));
typedef float f32x4  __attribute__((ext_vector_type(4)));

__device__ __forceinline__ void t2_insert(u64* a, u64 k) {
    u64 lo = a[0], hi = a[1];
    bool lt0 = k < lo;
    u64 n1k = (k < hi) ? k : hi;
    a[0] = lt0 ? k : lo;
    a[1] = lt0 ? lo : n1k;
}

// ---------------- Kernel P: precompute bf16 bit-truncation splits (verified r5) ----
__global__ void vq_split_kernel(const float* __restrict__ x, const float* __restrict__ cb,
                                u16* __restrict__ xhi, u16* __restrict__ xmid,
                                u16* __restrict__ cbhi, u16* __restrict__ cbmid) {
    size_t t = (size_t)blockIdx.x * blockDim.x + threadIdx.x;
    const size_t nx = (size_t)N_ROWS * DIM / 4;
    const size_t nc = (size_t)K_CODES * DIM / 4;
    const float4* src;
    u16 *hi, *mid;
    size_t off;
    if (t < nx)            { src = (const float4*)x;  hi = xhi;  mid = xmid;  off = t; }
    else if (t < nx + nc)  { src = (const float4*)cb; hi = cbhi; mid = cbmid; off = t - nx; }
    else return;
    float4 v = src[off];
    u32 b0 = __float_as_uint(v.x), b1 = __float_as_uint(v.y),
        b2 = __float_as_uint(v.z), b3 = __float_as_uint(v.w);
    u16 h0 = (u16)(b0 >> 16), h1 = (u16)(b1 >> 16), h2 = (u16)(b2 >> 16), h3 = (u16)(b3 >> 16);
    u16 m0 = (u16)(__float_as_uint(v.x - __uint_as_float(b0 & 0xFFFF0000u)) >> 16);
    u16 m1 = (u16)(__float_as_uint(v.y - __uint_as_float(b1 & 0xFFFF0000u)) >> 16);
    u16 m2 = (u16)(__float_as_uint(v.z - __uint_as_float(b2 & 0xFFFF0000u)) >> 16);
    u16 m3 = (u16)(__float_as_uint(v.w - __uint_as_float(b3 & 0xFFFF0000u)) >> 16);
    ((ushort4*)hi)[off]  = make_ushort4(h0, h1, h2, h3);
    ((ushort4*)mid)[off] = make_ushort4(m0, m1, m2, m3);
}

// ---------------- Kernel N: numpy-pairwise fp32 row norms (verified r3) ----------------
__device__ __forceinline__ float np_block128_sq(const float* __restrict__ q) {
    float r[8];
    #pragma unroll
    for (int j = 0; j < 8; ++j) r[j] = __fmul_rn(q[j], q[j]);
    for (int i = 8; i < 128; i += 8) {
        #pragma unroll
        for (int j = 0; j < 8; ++j) r[j] = __fadd_rn(r[j], __fmul_rn(q[i + j], q[i + j]));
    }
    return __fadd_rn(__fadd_rn(__fadd_rn(r[0], r[1]), __fadd_rn(r[2], r[3])),
                     __fadd_rn(__fadd_rn(r[4], r[5]), __fadd_rn(r[6], r[7])));
}

__global__ void vq_np_norm_kernel(const float* __restrict__ x, const float* __restrict__ cb,
                                  float* __restrict__ Arow, float* __restrict__ Bcode) {
    int t = blockIdx.x * blockDim.x + threadIdx.x;
    const float* p;
    float* o;
    if (t < N_ROWS) {
        p = x + (size_t)t * DIM;  o = Arow + t;
    } else if (t < N_ROWS + K_CODES) {
        int j = t - N_ROWS;
        p = cb + (size_t)j * DIM; o = Bcode + j;
    } else return;
    float b0 = np_block128_sq(p);
    float b1 = np_block128_sq(p + 128);
    float b2 = np_block128_sq(p + 256);
    float b3 = np_block128_sq(p + 384);
    *o = __fadd_rn(__fadd_rn(b0, b1), __fadd_rn(b2, b3));
}

// ---------------- Kernel S: MFMA screen, 256x256 block, K-only staging ----------------
// 8 waves (2M x 4N grid? no: 4M-row x 2N-col of 64x128 wave tiles). Wave tile 64x128:
// A-frags (2 planes) loaded once per kt serve 8 ni -> 24 ds_reads per 96 MFMA.
// LDS 2 x 64KB dbuf; global_load_lds w16, 8 per wave per stage, counted vmcnt(8).
// Per-acc-element MFMA order identical to r5-r7 (kt asc x {hh,hm,mh}).
__launch_bounds__(512, 2)
__global__ void vq_screen_kernel(const u16* __restrict__ xhi, const u16* __restrict__ xmid,
                                 const u16* __restrict__ cbhi, const u16* __restrict__ cbmid,
                                 const float* __restrict__ Arow,
                                 const float* __restrict__ Bcode,
                                 u64* __restrict__ top2out) {
    __shared__ __align__(16) u16 lds[2][32768];   // 2 x 64KB: planes AH|AM|BH|BM, each [256][32]

    const int t = threadIdx.x;
    const int lane = t & 63;
    const int w = t >> 6;        // 0..7
    const int wm = w >> 1;       // 0..3 -> rows [64*wm, +64)
    const int wn = w & 1;        // 0..1 -> cols [128*wn, +128)
    const int r15 = lane & 15;
    const int g = lane >> 4;     // 0..3

    const int rowBase   = blockIdx.x * BMS;
    const int chunk     = blockIdx.y;
    const int chunkBase = chunk * CHUNK_CODES;

    const u16* gp0 = xhi   + (size_t)rowBase * DIM;
    const u16* gp1 = xmid  + (size_t)rowBase * DIM;
    const u16* gp2 = cbhi  + (size_t)chunkBase * DIM;
    const u16* gp3 = cbmid + (size_t)chunkBase * DIM;
    // lane -> (row within 16-row group, k-chunk): matches LDS [row][32] layout linearly
    const size_t laneOff = (size_t)(lane >> 2) * DIM + (size_t)((lane & 3) * 8);

    f32x4 acc[4][8] = {};

    // ---- staging: plane p, half h -> rows [128h + 16w, +16), dest plane + 4096h + 512w
    auto stage = [&](int kt, u16* ldsb) {
        #pragma unroll
        for (int p = 0; p < 4; ++p) {
            const u16* gp = (p == 0) ? gp0 : (p == 1) ? gp1 : (p == 2) ? gp2 : gp3;
            #pragma unroll
            for (int h = 0; h < 2; ++h) {
                const u16* src = gp + (size_t)(h * 128 + w * 16) * DIM + kt * KC + laneOff;
                u16* dst = ldsb + p * 8192 + h * 4096 + w * 512;
                __builtin_amdgcn_global_load_lds(
                    (const __attribute__((address_space(1))) u32*)src,
                    (__attribute__((address_space(3))) u32*)dst,
                    16, 0, 0);
            }
        }
    };

    auto body = [&](int kt, u16* L, u16* Lnext, bool last) {
        if (!last) {
            stage(kt + 1, Lnext);
            asm volatile("s_waitcnt vmcnt(8)" ::: "memory");
        } else {
            asm volatile("s_waitcnt vmcnt(0)" ::: "memory");
        }
        asm volatile("s_barrier" ::: "memory");

        bf16x8 Ah[4], Am[4];
        #pragma unroll
        for (int mi = 0; mi < 4; ++mi) {
            int a = (wm * 64 + mi * 16 + r15) * 32 + g * 8;
            Ah[mi] = *(const bf16x8*)&L[a];
            Am[mi] = *(const bf16x8*)&L[8192 + a];
        }
        __builtin_amdgcn_s_setprio(1);
        #pragma unroll
        for (int ni = 0; ni < 8; ++ni) {
            int b = (wn * 128 + ni * 16 + r15) * 32 + g * 8;
            bf16x8 Bh = *(const bf16x8*)&L[16384 + b];
            bf16x8 Bm = *(const bf16x8*)&L[24576 + b];
            #pragma unroll
            for (int mi = 0; mi < 4; ++mi) {
                acc[mi][ni] = __builtin_amdgcn_mfma_f32_16x16x32_bf16(Ah[mi], Bh, acc[mi][ni], 0, 0, 0);
                acc[mi][ni] = __builtin_amdgcn_mfma_f32_16x16x32_bf16(Ah[mi], Bm, acc[mi][ni], 0, 0, 0);
                acc[mi][ni] = __builtin_amdgcn_mfma_f32_16x16x32_bf16(Am[mi], Bh, acc[mi][ni], 0, 0, 0);
            }
        }
        __builtin_amdgcn_s_setprio(0);
        asm volatile("s_barrier" ::: "memory");
    };

    stage(0, &lds[0][0]);
    #pragma unroll
    for (int k2 = 0; k2 < KSTAGES / 2; ++k2) {
        body(2 * k2,     &lds[0][0], &lds[1][0], false);
        body(2 * k2 + 1, &lds[1][0], &lds[0][0], (2 * k2 + 1) == KSTAGES - 1);
    }

    // ---- fold once: full-K acc -> np-fp32 dist -> per-row top-2 of this chunk ----
    u64 t2[4][4][2];
    #pragma unroll
    for (int mi = 0; mi < 4; ++mi)
        #pragma unroll
        for (int reg = 0; reg < 4; ++reg) { t2[mi][reg][0] = ~0ull; t2[mi][reg][1] = ~0ull; }

    float bjv[8];
    #pragma unroll
    for (int ni = 0; ni < 8; ++ni)
        bjv[ni] = Bcode[chunkBase + wn * 128 + ni * 16 + r15];

    #pragma unroll
    for (int mi = 0; mi < 4; ++mi) {
        float AiV[4];
        #pragma unroll
        for (int reg = 0; reg < 4; ++reg)
            AiV[reg] = Arow[rowBase + wm * 64 + mi * 16 + g * 4 + reg];
        #pragma unroll
        for (int ni = 0; ni < 8; ++ni) {
            int col = chunkBase + wn * 128 + ni * 16 + r15;
            #pragma unroll
            for (int reg = 0; reg < 4; ++reg) {
                float d = __fsub_rn(__fadd_rn(AiV[reg], bjv[ni]), 2.0f * acc[mi][ni][reg]);
                u64 key = ((u64)__float_as_uint(d) << 13) | (u64)(u32)col;
                t2_insert(t2[mi][reg], key);
            }
        }
    }

    // ---- merge across the 16 column-lanes ----
    #pragma unroll
    for (int m = 1; m <= 8; m <<= 1) {
        #pragma unroll
        for (int mi = 0; mi < 4; ++mi)
            #pragma unroll
            for (int reg = 0; reg < 4; ++reg) {
                u64 i0 = __shfl_xor(t2[mi][reg][0], m);
                u64 i1 = __shfl_xor(t2[mi][reg][1], m);
                t2_insert(t2[mi][reg], i0);
                t2_insert(t2[mi][reg], i1);
            }
    }

    // ---- merge across the 2 wn waves via LDS, write chunk top-2 ----
    __syncthreads();
    u64* t2buf = (u64*)&lds[0][0];   // [256 rows][2 wn][2 slots]
    if (r15 == 0) {
        #pragma unroll
        for (int mi = 0; mi < 4; ++mi)
            #pragma unroll
            for (int reg = 0; reg < 4; ++reg) {
                int row = wm * 64 + mi * 16 + g * 4 + reg;
                t2buf[(row * 2 + wn) * 2 + 0] = t2[mi][reg][0];
                t2buf[(row * 2 + wn) * 2 + 1] = t2[mi][reg][1];
            }
    }
    __syncthreads();
    if (t < BMS) {
        u64 best[2];
        best[0] = t2buf[(t * 2 + 0) * 2 + 0];
        best[1] = t2buf[(t * 2 + 0) * 2 + 1];
        t2_insert(best, t2buf[(t * 2 + 1) * 2 + 0]);
        t2_insert(best, t2buf[(t * 2 + 1) * 2 + 1]);
        top2out[((size_t)chunk * N_ROWS + rowBase + t) * 2 + 0] = best[0];
        top2out[((size_t)chunk * N_ROWS + rowBase + t) * 2 + 1] = best[1];
    }
}

// ---------------- Kernel R: chunk-top2 -> slice-top2 -> exact np re-decision ----------------
__global__ void vq_refine_kernel(const float* __restrict__ x, const float* __restrict__ cb,
                                 const float* __restrict__ Arow, const float* __restrict__ Bcode,
                                 const u64* __restrict__ top2, int* __restrict__ idxOut,
                                 float* __restrict__ out4) {
    int gw = (blockIdx.x * blockDim.x + threadIdx.x) >> 6;
    int lane = threadIdx.x & 63;
    if (gw >= N_ROWS) return;

    // lane <-> (chunk = lane>>1, slot = lane&1); slice s = lanes [16s,16s+16) (chunks 8s..8s+7)
    u64 key = top2[((size_t)(lane >> 1) * N_ROWS + gw) * 2 + (lane & 1)];

    u64 m1 = key;
    #pragma unroll
    for (int m = 1; m < 16; m <<= 1) { u64 o = __shfl_xor(m1, m); m1 = o < m1 ? o : m1; }
    u64 k2 = (key == m1) ? ~0ull : key;
    u64 m2 = k2;
    #pragma unroll
    for (int m = 1; m < 16; m <<= 1) { u64 o = __shfl_xor(m2, m); m2 = o < m2 ? o : m2; }

    float Ai = Arow[gw];
    const float* xr = x + (size_t)gw * DIM;
    u64 best = ~0ull;
    #pragma unroll
    for (int j = 0; j < 8; ++j) {
        u64 ck = __shfl((j & 1) ? m2 : m1, (j >> 1) * 16);
        int c = (int)(ck & 8191u);
        const float* er = cb + (size_t)c * DIM;
        double d = 0.0;
        #pragma unroll
        for (int e = 0; e < 8; ++e)
            d = fma((double)xr[e * 64 + lane], (double)er[e * 64 + lane], d);
        #pragma unroll
        for (int m = 1; m < 64; m <<= 1) d += __shfl_xor(d, m);
        float m32 = (float)d;
        float dist = __fsub_rn(__fadd_rn(Ai, Bcode[c]), 2.0f * m32);
        u64 ek = ((u64)__float_as_uint(dist) << 13) | (u64)(u32)c;
        best = ek < best ? ek : best;
    }
    if (lane == 0) {
        int c = (int)(best & 8191u);
        idxOut[gw] = c;
        out4[gw] = (float)c;
    }
}

// ---------------- Kernel C: gather + outputs + per-row loss partial ----------------
__global__ void vq_gather_kernel(const float* __restrict__ x,
                                 const float* __restrict__ cb,
                                 const int* __restrict__ idxArr,
                                 float* __restrict__ out0,
                                 float* __restrict__ out3,
                                 float* __restrict__ rowPart) {
    int gw = (blockIdx.x * blockDim.x + threadIdx.x) >> 6;
    int lane = threadIdx.x & 63;
    if (gw >= N_ROWS) return;
    int idx = idxArr[gw];
    const float2* xp = (const float2*)(x  + (size_t)gw * DIM);
    const float2* qp = (const float2*)(cb + (size_t)idx * DIM);
    float2* o0 = (float2*)(out0 + (size_t)gw * DIM);
    float2* o3 = (float2*)(out3 + (size_t)gw * DIM);
    float part = 0.0f;
    #pragma unroll
    for (int r = 0; r < 4; ++r) {
        int e = r * 64 + lane;
        float2 xv = xp[e];
        float2 qv = qp[e];
        float dx = qv.x - xv.x, dy = qv.y - xv.y;
        part += dx * dx + dy * dy;
        float2 o; o.x = xv.x + dx; o.y = xv.y + dy;
        o0[e] = o;
        o3[e] = qv;
    }
    #pragma unroll
    for (int m = 32; m; m >>= 1) part += __shfl_xor(part, m);
    if (lane == 0) rowPart[gw] = part;
}

// ---------------- Kernel D: deterministic loss reduce ----------------
__global__ void vq_loss_kernel(const float* __restrict__ rowPart,
                               float* __restrict__ out1, float* __restrict__ out2) {
    __shared__ float red[256];
    int t = threadIdx.x;
    float s = 0.0f;
    for (int r = t; r < N_ROWS; r += 256) s += rowPart[r];
    red[t] = s;
    __syncthreads();
    #pragma unroll
    for (int m = 128; m; m >>= 1) {
        if (t < m) red[t] += red[t + m];
        __syncthreads();
    }
    if (t == 0) {
        float loss = red[0] / (float)(N_ROWS * DIM);
        out1[0] = loss;
        out2[0] = loss;
    }
}

extern "C" void kernel_launch(void* const* d_in, const int* in_sizes, int n_in,
                              void* d_out, int out_size, void* d_ws, size_t ws_size,
                              hipStream_t stream) {
    const float* x  = (const float*)d_in[0];   // [16384, 512]
    const float* cb = (const float*)d_in[1];   // [8192, 512]
    float* out  = (float*)d_out;
    float* out0 = out;                         // quantized_out [8388608]
    float* out1 = out + 8388608;               // q_latent_loss [1]
    float* out2 = out + 8388609;               // e_latent_loss [1]
    float* out3 = out + 8388610;               // quantized [8388608]
    float* out4 = out + 16777218;              // idx as float [16384]

    // d_out doubles as scratch until refine/gather consume & overwrite (stream-ordered):
    // splits in [0, 12582916); chunk-top2 in the out3 tail [12582916, 14680068).
    u16* xhi   = (u16*)out0;                       // [0, 4194304) floats
    u16* xmid  = (u16*)(out + 4194304);            // [4194304, 8388608)
    u16* cbhi  = (u16*)(out + 8388612);            // [8388612, 10485764)  16B-aligned
    u16* cbmid = (u16*)(out + 10485764);           // [10485764, 12582916)
    u64* wsTop2 = (u64*)(out + 12582916);          // 32*16384*2 u64 = 8MB

    char* ws = (char*)d_ws;
    float* wsA    = (float*)ws;                    // 16384 f
    float* wsB    = (float*)(ws + 65536);          // 8192 f
    int*   wsIdx  = (int*)(ws + 98304);            // 16384 int
    float* wsPart = (float*)(ws + 163840);         // 16384 f

    hipLaunchKernelGGL(vq_split_kernel,   dim3(12288), dim3(256), 0, stream,
                       x, cb, xhi, xmid, cbhi, cbmid);
    hipLaunchKernelGGL(vq_np_norm_kernel, dim3(96), dim3(256), 0, stream, x, cb, wsA, wsB);
    hipLaunchKernelGGL(vq_screen_kernel,  dim3(N_ROWS / BMS, CHUNKS), dim3(512), 0, stream,
                       xhi, xmid, cbhi, cbmid, wsA, wsB, wsTop2);
    hipLaunchKernelGGL(vq_refine_kernel,  dim3(4096), dim3(256), 0, stream,
                       x, cb, wsA, wsB, wsTop2, wsIdx, out4);
    hipLaunchKernelGGL(vq_gather_kernel,  dim3(4096), dim3(256), 0, stream,
                       x, cb, wsIdx, out0, out3, wsPart);
    hipLaunchKernelGGL(vq_loss_kernel,    dim3(1),   dim3(256), 0, stream,
                       wsPart, out1, out2);
}

// Round 9
// 576.496 us; speedup vs baseline: 1.0166x; 1.0166x over previous
//
#include <hip/hip_runtime.h>

typedef unsigned long long u64;
typedef unsigned int u32;
typedef unsigned short u16;

#define N_ROWS 16384
#define DIM    512
#define K_CODES 8192

#define CHUNKS 32
#define CHUNK_CODES 256
#define BMS 256
#define KC 32
#define KSTAGES (DIM / KC)   // 16

typedef short bf16x8 __attribute__((ext_vector_type(8)));
typedef float f32x4  __attribute__((ext_vector_type(4)));

__device__ __forceinline__ void t2_insert(u64* a, u64 k) {
    u64 lo = a[0], hi = a[1];
    bool lt0 = k < lo;
    u64 n1k = (k < hi) ? k : hi;
    a[0] = lt0 ? k : lo;
    a[1] = lt0 ? lo : n1k;
}

// ---------------- Kernel P: precompute bf16 bit-truncation splits (verified r5) ----
__global__ void vq_split_kernel(const float* __restrict__ x, const float* __restrict__ cb,
                                u16* __restrict__ xhi, u16* __restrict__ xmid,
                                u16* __restrict__ cbhi, u16* __restrict__ cbmid) {
    size_t t = (size_t)blockIdx.x * blockDim.x + threadIdx.x;
    const size_t nx = (size_t)N_ROWS * DIM / 4;
    const size_t nc = (size_t)K_CODES * DIM / 4;
    const float4* src;
    u16 *hi, *mid;
    size_t off;
    if (t < nx)            { src = (const float4*)x;  hi = xhi;  mid = xmid;  off = t; }
    else if (t < nx + nc)  { src = (const float4*)cb; hi = cbhi; mid = cbmid; off = t - nx; }
    else return;
    float4 v = src[off];
    u32 b0 = __float_as_uint(v.x), b1 = __float_as_uint(v.y),
        b2 = __float_as_uint(v.z), b3 = __float_as_uint(v.w);
    u16 h0 = (u16)(b0 >> 16), h1 = (u16)(b1 >> 16), h2 = (u16)(b2 >> 16), h3 = (u16)(b3 >> 16);
    u16 m0 = (u16)(__float_as_uint(v.x - __uint_as_float(b0 & 0xFFFF0000u)) >> 16);
    u16 m1 = (u16)(__float_as_uint(v.y - __uint_as_float(b1 & 0xFFFF0000u)) >> 16);
    u16 m2 = (u16)(__float_as_uint(v.z - __uint_as_float(b2 & 0xFFFF0000u)) >> 16);
    u16 m3 = (u16)(__float_as_uint(v.w - __uint_as_float(b3 & 0xFFFF0000u)) >> 16);
    ((ushort4*)hi)[off]  = make_ushort4(h0, h1, h2, h3);
    ((ushort4*)mid)[off] = make_ushort4(m0, m1, m2, m3);
}

// ---------------- Kernel N: numpy-pairwise fp32 row norms (verified r3) ----------------
__device__ __forceinline__ float np_block128_sq(const float* __restrict__ q) {
    float r[8];
    #pragma unroll
    for (int j = 0; j < 8; ++j) r[j] = __fmul_rn(q[j], q[j]);
    for (int i = 8; i < 128; i += 8) {
        #pragma unroll
        for (int j = 0; j < 8; ++j) r[j] = __fadd_rn(r[j], __fmul_rn(q[i + j], q[i + j]));
    }
    return __fadd_rn(__fadd_rn(__fadd_rn(r[0], r[1]), __fadd_rn(r[2], r[3])),
                     __fadd_rn(__fadd_rn(r[4], r[5]), __fadd_rn(r[6], r[7])));
}

__global__ void vq_np_norm_kernel(const float* __restrict__ x, const float* __restrict__ cb,
                                  float* __restrict__ Arow, float* __restrict__ Bcode) {
    int t = blockIdx.x * blockDim.x + threadIdx.x;
    const float* p;
    float* o;
    if (t < N_ROWS) {
        p = x + (size_t)t * DIM;  o = Arow + t;
    } else if (t < N_ROWS + K_CODES) {
        int j = t - N_ROWS;
        p = cb + (size_t)j * DIM; o = Bcode + j;
    } else return;
    float b0 = np_block128_sq(p);
    float b1 = np_block128_sq(p + 128);
    float b2 = np_block128_sq(p + 256);
    float b3 = np_block128_sq(p + 384);
    *o = __fadd_rn(__fadd_rn(b0, b1), __fadd_rn(b2, b3));
}

// ---------------- Kernel S: MFMA screen, 256x256 block, K-only staging ----------------
// 8 waves = 4M x 2N of 64x128 wave tiles; 24 ds_read_b128 per 96 MFMA (64 FLOP/B).
// LDS 2x64KB dbuf, global_load_lds w16 counted vmcnt(8). Chunk-XOR swizzle
// c' = c ^ ((row>>1)&3) applied on BOTH sides (pre-swizzled global source, swizzled
// fragment read) -> 2-way max bank aliasing (free). MFMA order identical to r5-r8.
__launch_bounds__(512, 2)
__global__ void vq_screen_kernel(const u16* __restrict__ xhi, const u16* __restrict__ xmid,
                                 const u16* __restrict__ cbhi, const u16* __restrict__ cbmid,
                                 const float* __restrict__ Arow,
                                 const float* __restrict__ Bcode,
                                 u64* __restrict__ top2out) {
    __shared__ __align__(16) u16 lds[2][32768];   // 2 x 64KB: planes AH|AM|BH|BM, each [256][32]

    const int t = threadIdx.x;
    const int lane = t & 63;
    const int w = t >> 6;        // 0..7
    const int wm = w >> 1;       // 0..3 -> rows [64*wm, +64)
    const int wn = w & 1;        // 0..1 -> cols [128*wn, +128)
    const int r15 = lane & 15;
    const int g = lane >> 4;     // 0..3
    const int cswz = (r15 >> 1) & 3;   // read-side chunk XOR (row bases are mult of 16)

    const int rowBase   = blockIdx.x * BMS;
    const int chunk     = blockIdx.y;
    const int chunkBase = chunk * CHUNK_CODES;

    const u16* gp0 = xhi   + (size_t)rowBase * DIM;
    const u16* gp1 = xmid  + (size_t)rowBase * DIM;
    const u16* gp2 = cbhi  + (size_t)chunkBase * DIM;
    const u16* gp3 = cbmid + (size_t)chunkBase * DIM;
    // lane -> (row in 16-row group, PRE-SWIZZLED source chunk); LDS dest stays linear
    const size_t laneOff = (size_t)(lane >> 2) * DIM
                         + (size_t)(((lane & 3) ^ ((lane >> 3) & 3)) * 8);

    f32x4 acc[4][8] = {};

    // ---- staging: plane p, half h -> rows [128h + 16w, +16), dest plane + 4096h + 512w
    auto stage = [&](int kt, u16* ldsb) {
        #pragma unroll
        for (int p = 0; p < 4; ++p) {
            const u16* gp = (p == 0) ? gp0 : (p == 1) ? gp1 : (p == 2) ? gp2 : gp3;
            #pragma unroll
            for (int h = 0; h < 2; ++h) {
                const u16* src = gp + (size_t)(h * 128 + w * 16) * DIM + kt * KC + laneOff;
                u16* dst = ldsb + p * 8192 + h * 4096 + w * 512;
                __builtin_amdgcn_global_load_lds(
                    (const __attribute__((address_space(1))) u32*)src,
                    (__attribute__((address_space(3))) u32*)dst,
                    16, 0, 0);
            }
        }
    };

    auto body = [&](int kt, u16* L, u16* Lnext, bool last) {
        if (!last) {
            stage(kt + 1, Lnext);
            asm volatile("s_waitcnt vmcnt(8)" ::: "memory");
        } else {
            asm volatile("s_waitcnt vmcnt(0)" ::: "memory");
        }
        asm volatile("s_barrier" ::: "memory");

        bf16x8 Ah[4], Am[4];
        #pragma unroll
        for (int mi = 0; mi < 4; ++mi) {
            int a = (wm * 64 + mi * 16 + r15) * 32 + (g ^ cswz) * 8;
            Ah[mi] = *(const bf16x8*)&L[a];
            Am[mi] = *(const bf16x8*)&L[8192 + a];
        }
        __builtin_amdgcn_s_setprio(1);
        #pragma unroll
        for (int ni = 0; ni < 8; ++ni) {
            int b = (wn * 128 + ni * 16 + r15) * 32 + (g ^ cswz) * 8;
            bf16x8 Bh = *(const bf16x8*)&L[16384 + b];
            bf16x8 Bm = *(const bf16x8*)&L[24576 + b];
            #pragma unroll
            for (int mi = 0; mi < 4; ++mi) {
                acc[mi][ni] = __builtin_amdgcn_mfma_f32_16x16x32_bf16(Ah[mi], Bh, acc[mi][ni], 0, 0, 0);
                acc[mi][ni] = __builtin_amdgcn_mfma_f32_16x16x32_bf16(Ah[mi], Bm, acc[mi][ni], 0, 0, 0);
                acc[mi][ni] = __builtin_amdgcn_mfma_f32_16x16x32_bf16(Am[mi], Bh, acc[mi][ni], 0, 0, 0);
            }
        }
        __builtin_amdgcn_s_setprio(0);
        asm volatile("s_barrier" ::: "memory");
    };

    stage(0, &lds[0][0]);
    #pragma unroll
    for (int k2 = 0; k2 < KSTAGES / 2; ++k2) {
        body(2 * k2,     &lds[0][0], &lds[1][0], false);
        body(2 * k2 + 1, &lds[1][0], &lds[0][0], (2 * k2 + 1) == KSTAGES - 1);
    }

    // ---- fold once: full-K acc -> np-fp32 dist -> per-row top-2 of this chunk ----
    u64 t2[4][4][2];
    #pragma unroll
    for (int mi = 0; mi < 4; ++mi)
        #pragma unroll
        for (int reg = 0; reg < 4; ++reg) { t2[mi][reg][0] = ~0ull; t2[mi][reg][1] = ~0ull; }

    float bjv[8];
    #pragma unroll
    for (int ni = 0; ni < 8; ++ni)
        bjv[ni] = Bcode[chunkBase + wn * 128 + ni * 16 + r15];

    #pragma unroll
    for (int mi = 0; mi < 4; ++mi) {
        float AiV[4];
        #pragma unroll
        for (int reg = 0; reg < 4; ++reg)
            AiV[reg] = Arow[rowBase + wm * 64 + mi * 16 + g * 4 + reg];
        #pragma unroll
        for (int ni = 0; ni < 8; ++ni) {
            int col = chunkBase + wn * 128 + ni * 16 + r15;
            #pragma unroll
            for (int reg = 0; reg < 4; ++reg) {
                float d = __fsub_rn(__fadd_rn(AiV[reg], bjv[ni]), 2.0f * acc[mi][ni][reg]);
                u64 key = ((u64)__float_as_uint(d) << 13) | (u64)(u32)col;
                t2_insert(t2[mi][reg], key);
            }
        }
    }

    // ---- merge across the 16 column-lanes ----
    #pragma unroll
    for (int m = 1; m <= 8; m <<= 1) {
        #pragma unroll
        for (int mi = 0; mi < 4; ++mi)
            #pragma unroll
            for (int reg = 0; reg < 4; ++reg) {
                u64 i0 = __shfl_xor(t2[mi][reg][0], m);
                u64 i1 = __shfl_xor(t2[mi][reg][1], m);
                t2_insert(t2[mi][reg], i0);
                t2_insert(t2[mi][reg], i1);
            }
    }

    // ---- merge across the 2 wn waves via LDS, write chunk top-2 ----
    __syncthreads();
    u64* t2buf = (u64*)&lds[0][0];   // [256 rows][2 wn][2 slots]
    if (r15 == 0) {
        #pragma unroll
        for (int mi = 0; mi < 4; ++mi)
            #pragma unroll
            for (int reg = 0; reg < 4; ++reg) {
                int row = wm * 64 + mi * 16 + g * 4 + reg;
                t2buf[(row * 2 + wn) * 2 + 0] = t2[mi][reg][0];
                t2buf[(row * 2 + wn) * 2 + 1] = t2[mi][reg][1];
            }
    }
    __syncthreads();
    if (t < BMS) {
        u64 best[2];
        best[0] = t2buf[(t * 2 + 0) * 2 + 0];
        best[1] = t2buf[(t * 2 + 0) * 2 + 1];
        t2_insert(best, t2buf[(t * 2 + 1) * 2 + 0]);
        t2_insert(best, t2buf[(t * 2 + 1) * 2 + 1]);
        top2out[((size_t)chunk * N_ROWS + rowBase + t) * 2 + 0] = best[0];
        top2out[((size_t)chunk * N_ROWS + rowBase + t) * 2 + 1] = best[1];
    }
}

// ---------------- Kernel R: chunk-top2 -> slice-top2 -> exact np re-decision ----------------
__global__ void vq_refine_kernel(const float* __restrict__ x, const float* __restrict__ cb,
                                 const float* __restrict__ Arow, const float* __restrict__ Bcode,
                                 const u64* __restrict__ top2, int* __restrict__ idxOut,
                                 float* __restrict__ out4) {
    int gw = (blockIdx.x * blockDim.x + threadIdx.x) >> 6;
    int lane = threadIdx.x & 63;
    if (gw >= N_ROWS) return;

    // lane <-> (chunk = lane>>1, slot = lane&1); slice s = lanes [16s,16s+16) (chunks 8s..8s+7)
    u64 key = top2[((size_t)(lane >> 1) * N_ROWS + gw) * 2 + (lane & 1)];

    u64 m1 = key;
    #pragma unroll
    for (int m = 1; m < 16; m <<= 1) { u64 o = __shfl_xor(m1, m); m1 = o < m1 ? o : m1; }
    u64 k2 = (key == m1) ? ~0ull : key;
    u64 m2 = k2;
    #pragma unroll
    for (int m = 1; m < 16; m <<= 1) { u64 o = __shfl_xor(m2, m); m2 = o < m2 ? o : m2; }

    float Ai = Arow[gw];
    const float* xr = x + (size_t)gw * DIM;
    u64 best = ~0ull;
    #pragma unroll
    for (int j = 0; j < 8; ++j) {
        u64 ck = __shfl((j & 1) ? m2 : m1, (j >> 1) * 16);
        int c = (int)(ck & 8191u);
        const float* er = cb + (size_t)c * DIM;
        double d = 0.0;
        #pragma unroll
        for (int e = 0; e < 8; ++e)
            d = fma((double)xr[e * 64 + lane], (double)er[e * 64 + lane], d);
        #pragma unroll
        for (int m = 1; m < 64; m <<= 1) d += __shfl_xor(d, m);
        float m32 = (float)d;
        float dist = __fsub_rn(__fadd_rn(Ai, Bcode[c]), 2.0f * m32);
        u64 ek = ((u64)__float_as_uint(dist) << 13) | (u64)(u32)c;
        best = ek < best ? ek : best;
    }
    if (lane == 0) {
        int c = (int)(best & 8191u);
        idxOut[gw] = c;
        out4[gw] = (float)c;
    }
}

// ---------------- Kernel C: gather + outputs + per-row loss partial ----------------
__global__ void vq_gather_kernel(const float* __restrict__ x,
                                 const float* __restrict__ cb,
                                 const int* __restrict__ idxArr,
                                 float* __restrict__ out0,
                                 float* __restrict__ out3,
                                 float* __restrict__ rowPart) {
    int gw = (blockIdx.x * blockDim.x + threadIdx.x) >> 6;
    int lane = threadIdx.x & 63;
    if (gw >= N_ROWS) return;
    int idx = idxArr[gw];
    const float2* xp = (const float2*)(x  + (size_t)gw * DIM);
    const float2* qp = (const float2*)(cb + (size_t)idx * DIM);
    float2* o0 = (float2*)(out0 + (size_t)gw * DIM);
    float2* o3 = (float2*)(out3 + (size_t)gw * DIM);
    float part = 0.0f;
    #pragma unroll
    for (int r = 0; r < 4; ++r) {
        int e = r * 64 + lane;
        float2 xv = xp[e];
        float2 qv = qp[e];
        float dx = qv.x - xv.x, dy = qv.y - xv.y;
        part += dx * dx + dy * dy;
        float2 o; o.x = xv.x + dx; o.y = xv.y + dy;
        o0[e] = o;
        o3[e] = qv;
    }
    #pragma unroll
    for (int m = 32; m; m >>= 1) part += __shfl_xor(part, m);
    if (lane == 0) rowPart[gw] = part;
}

// ---------------- Kernel D: deterministic loss reduce ----------------
__global__ void vq_loss_kernel(const float* __restrict__ rowPart,
                               float* __restrict__ out1, float* __restrict__ out2) {
    __shared__ float red[256];
    int t = threadIdx.x;
    float s = 0.0f;
    for (int r = t; r < N_ROWS; r += 256) s += rowPart[r];
    red[t] = s;
    __syncthreads();
    #pragma unroll
    for (int m = 128; m; m >>= 1) {
        if (t < m) red[t] += red[t + m];
        __syncthreads();
    }
    if (t == 0) {
        float loss = red[0] / (float)(N_ROWS * DIM);
        out1[0] = loss;
        out2[0] = loss;
    }
}

extern "C" void kernel_launch(void* const* d_in, const int* in_sizes, int n_in,
                              void* d_out, int out_size, void* d_ws, size_t ws_size,
                              hipStream_t stream) {
    const float* x  = (const float*)d_in[0];   // [16384, 512]
    const float* cb = (const float*)d_in[1];   // [8192, 512]
    float* out  = (float*)d_out;
    float* out0 = out;                         // quantized_out [8388608]
    float* out1 = out + 8388608;               // q_latent_loss [1]
    float* out2 = out + 8388609;               // e_latent_loss [1]
    float* out3 = out + 8388610;               // quantized [8388608]
    float* out4 = out + 16777218;              // idx as float [16384]

    // d_out doubles as scratch until refine/gather consume & overwrite (stream-ordered):
    // splits in [0, 12582916); chunk-top2 in the out3 tail [12582916, 14680068).
    u16* xhi   = (u16*)out0;                       // [0, 4194304) floats
    u16* xmid  = (u16*)(out + 4194304);            // [4194304, 8388608)
    u16* cbhi  = (u16*)(out + 8388612);            // [8388612, 10485764)  16B-aligned
    u16* cbmid = (u16*)(out + 10485764);           // [10485764, 12582916)
    u64* wsTop2 = (u64*)(out + 12582916);          // 32*16384*2 u64 = 8MB

    char* ws = (char*)d_ws;
    float* wsA    = (float*)ws;                    // 16384 f
    float* wsB    = (float*)(ws + 65536);          // 8192 f
    int*   wsIdx  = (int*)(ws + 98304);            // 16384 int
    float* wsPart = (float*)(ws + 163840);         // 16384 f

    hipLaunchKernelGGL(vq_split_kernel,   dim3(12288), dim3(256), 0, stream,
                       x, cb, xhi, xmid, cbhi, cbmid);
    hipLaunchKernelGGL(vq_np_norm_kernel, dim3(96), dim3(256), 0, stream, x, cb, wsA, wsB);
    hipLaunchKernelGGL(vq_screen_kernel,  dim3(N_ROWS / BMS, CHUNKS), dim3(512), 0, stream,
                       xhi, xmid, cbhi, cbmid, wsA, wsB, wsTop2);
    hipLaunchKernelGGL(vq_refine_kernel,  dim3(4096), dim3(256), 0, stream,
                       x, cb, wsA, wsB, wsTop2, wsIdx, out4);
    hipLaunchKernelGGL(vq_gather_kernel,  dim3(4096), dim3(256), 0, stream,
                       x, cb, wsIdx, out0, out3, wsPart);
    hipLaunchKernelGGL(vq_loss_kernel,    dim3(1),   dim3(256), 0, stream,
                       wsPart, out1, out2);
}